// Round 5
// baseline (362.475 us; speedup 1.0000x reference)
//
#include <hip/hip_runtime.h>

#define TAGS 256
#define RPW  8   // rows per wave, processed in batched phases

typedef float f32x4 __attribute__((ext_vector_type(4)));

// Wave w owns rows [8w, 8w+8). Phases:
//   1) 8 independent nontemporal float4 loads (8 KB in flight per wave)
//   2) lane-local max/first-idx per row; 6-step value-only shfl_xor
//      butterfly interleaved across the 8 rows (DS latency pipelines)
//   3) per-row ballot -> lowest set lane = first-occurrence argmax ->
//      v_readlane broadcast; 8 independent temporal gathers of
//      transitions[argmax] (kept cacheable: 256 KB table stays L2-hot)
//   4) add + 8 nontemporal stores
// Streams are nt so the single-use in/out traffic doesn't evict the table.
__global__ __launch_bounds__(256) void crf_head_kernel(
    const float* __restrict__ in,
    const float* __restrict__ trans,
    float* __restrict__ out,
    int rows)
{
    const int wave = (int)((blockIdx.x * blockDim.x + threadIdx.x) >> 6);
    const int lane = threadIdx.x & 63;
    const int r0   = wave * RPW;
    if (r0 >= rows) return;
    const int nv = (rows - r0 < RPW) ? (rows - r0) : RPW;  // wave-uniform

    // ---- phase 1: batched loads ----
    f32x4 v[RPW];
    #pragma unroll
    for (int j = 0; j < RPW; ++j)
        if (j < nv)
            v[j] = __builtin_nontemporal_load(
                       (const f32x4*)(in + (size_t)(r0 + j) * TAGS) + lane);

    // ---- phase 2: local max + interleaved butterflies ----
    float lm[RPW];  // lane-local max
    int   li[RPW];  // tag index of lane-local first max
    float m[RPW];   // running wave max
    #pragma unroll
    for (int j = 0; j < RPW; ++j) {
        if (j >= nv) continue;
        const float a = fmaxf(v[j][0], v[j][1]);
        const float b = fmaxf(v[j][2], v[j][3]);
        lm[j] = fmaxf(a, b);
        const int off = (v[j][0] == lm[j]) ? 0 : (v[j][1] == lm[j]) ? 1
                      : (v[j][2] == lm[j]) ? 2 : 3;
        li[j] = lane * 4 + off;
        m[j]  = lm[j];
    }
    #pragma unroll
    for (int s = 32; s >= 1; s >>= 1) {
        #pragma unroll
        for (int j = 0; j < RPW; ++j)
            if (j < nv)
                m[j] = fmaxf(m[j], __shfl_xor(m[j], s, 64));
    }

    // ---- phase 3: argmax recovery + batched gathers ----
    f32x4 t[RPW];
    #pragma unroll
    for (int j = 0; j < RPW; ++j) {
        if (j >= nv) continue;
        const unsigned long long mask = __ballot(lm[j] == m[j]);
        const int src = __ffsll((long long)mask) - 1;             // uniform
        const int mi  = __builtin_amdgcn_readlane(li[j], src);    // scalar
        t[j] = ((const f32x4*)(trans + (size_t)mi * TAGS))[lane]; // temporal
    }

    // ---- phase 4: add + batched stores ----
    #pragma unroll
    for (int j = 0; j < RPW; ++j) {
        if (j >= nv) continue;
        f32x4 o = v[j] + t[j];
        __builtin_nontemporal_store(
            o, (f32x4*)(out + (size_t)(r0 + j) * TAGS) + lane);
    }
}

extern "C" void kernel_launch(void* const* d_in, const int* in_sizes, int n_in,
                              void* d_out, int out_size, void* d_ws, size_t ws_size,
                              hipStream_t stream) {
    const float* in    = (const float*)d_in[0];   // [B, T, TAGS] fp32
    const float* trans = (const float*)d_in[1];   // [TAGS, TAGS] fp32
    float* out = (float*)d_out;                   // [B, T, TAGS] fp32

    const int rows  = in_sizes[0] / TAGS;         // B*T = 131072
    const int waves = (rows + RPW - 1) / RPW;     // 16384 waves
    const int blocks = (waves + 3) / 4;           // 4 waves / 256-thread block
    crf_head_kernel<<<dim3(blocks), dim3(256), 0, stream>>>(in, trans, out, rows);
}